// Round 11
// baseline (218.715 us; speedup 1.0000x reference)
//
#include <hip/hip_runtime.h>
#include <stdint.h>

// S6Layer on MI355X. B=8, L=4096, DM=256, DI=384, DS=8, CHUNK=32.
// R17 (this round): FUSE scan INTO GEMM1 -> s6_head. Session pattern: work-
// elimination wins (R9/R12/R16), schedule restructures lose (R10/R13/R15).
// R16 budget shows ~100us in the un-profiled tail (scan/ln well above their
// floors). s6_head: block = (128 tokens x 64 channels); 3 sub-GEMMs (xp, z,
// dt = W_eff) with the PROVEN R12 K-loop, sB (32KB) reused, results to three
// 16KB LDS arrays (col ^ (fq<<4) XOR layout: 2-way banks on epilogue write
// AND scan read since (row>>2)&3 == fq); then 256 (chunk,ch) scan units run
// from LDS (R13's fatal flaw was global scalar loads here), write only yz.
// xp/z/dt NEVER touch HBM (-96MB), one less launch. LDS exactly 80KB -> 2
// blocks/CU. XCD swizzle: xcd owns 32 m-tiles, sweeps 6 panels -> its 2.1MB
// xn slice stays L2-resident. Numerics bit-identical to R16 (same f2bf
// points) -> absmax 0.03125 expected unchanged.
// Pipeline: cvt, prep, ln, s6_head, GEMM3(EPI=3).
#define B_  8
#define L_  4096
#define DM  256
#define DI  384
#define DS  8
#define M_  (B_*L_)   // 32768 tokens

typedef float f32x4 __attribute__((ext_vector_type(4)));
typedef short s16x8 __attribute__((ext_vector_type(8)));

#define AS1(p) ((__attribute__((address_space(1))) void*)(p))
#define AS3(p) ((__attribute__((address_space(3))) void*)(p))

__device__ __forceinline__ unsigned short f2bf(float f) {
  union { float f; uint32_t u; } v; v.f = f;
  uint32_t r = v.u + 0x7FFFu + ((v.u >> 16) & 1u);   // RNE
  return (unsigned short)(r >> 16);
}
__device__ __forceinline__ float bf2f(unsigned short h) {
  union { uint32_t u; float f; } v; v.u = ((uint32_t)h) << 16;
  return v.f;
}
__device__ __forceinline__ float silu_f(float x) {
  return x * __builtin_amdgcn_rcpf(1.f + __expf(-x));
}

// ---------------- weight fp32 -> bf16 (+ b_in copy into combined bias) -----
__global__ __launch_bounds__(256) void cvt_kernel(
    const float* __restrict__ w0, const float* __restrict__ w2,
    const float* __restrict__ b_in,
    unsigned short* __restrict__ o0, unsigned short* __restrict__ o2,
    float* __restrict__ biasc) {
  int i = blockIdx.x * 256 + threadIdx.x;
  if (i < 3*DI*DM) o0[i] = f2bf(w0[i]);
  if (i < DM*DI)   o2[i] = f2bf(w2[i]);
  if (i < 2*DI)    biasc[i] = b_in[i];
}

// ---------------- prep: W_eff = W_dt @ W_in_dt, b_eff = W_dt@b_in_dt + b_dt
__global__ __launch_bounds__(256) void prep_kernel(
    const float* __restrict__ W_in, const float* __restrict__ b_in,
    const float* __restrict__ W_dt, const float* __restrict__ b_dt,
    unsigned short* __restrict__ winb, float* __restrict__ biasc) {
  int nb = blockIdx.x;
  if (nb < DI) {
    int c = threadIdx.x;                 // 0..DM-1
    float acc = 0.f;
    for (int k = 0; k < DI; ++k)
      acc += W_dt[(size_t)nb*DI + k] * W_in[(size_t)(2*DI + k)*DM + c];
    winb[(size_t)(2*DI + nb)*DM + c] = f2bf(acc);
  } else {
    int n = (nb - DI)*256 + threadIdx.x;
    if (n < DI) {
      float acc = b_dt[n];
      for (int k = 0; k < DI; ++k)
        acc += W_dt[(size_t)n*DI + k] * b_in[2*DI + k];
      biasc[2*DI + n] = acc;
    }
  }
}

// ---------------- layernorm: one wave per token ----------------
__global__ __launch_bounds__(256) void ln_kernel(
    const float* __restrict__ x, const float* __restrict__ gamma, const float* __restrict__ beta,
    unsigned short* __restrict__ xn) {
  int token = blockIdx.x * 4 + (threadIdx.x >> 6);
  int lane  = threadIdx.x & 63;
  const float4 v = *(const float4*)(x + (size_t)token*DM + lane*4);
  float s  = v.x + v.y + v.z + v.w;
  float ss = v.x*v.x + v.y*v.y + v.z*v.z + v.w*v.w;
  #pragma unroll
  for (int off = 32; off > 0; off >>= 1) {
    s  += __shfl_xor(s,  off, 64);
    ss += __shfl_xor(ss, off, 64);
  }
  float mean = s * (1.f/DM);
  float var  = ss * (1.f/DM) - mean*mean;
  float rstd = rsqrtf(var + 1e-5f);
  const float4 g = *(const float4*)(gamma + lane*4);
  const float4 b = *(const float4*)(beta  + lane*4);
  ushort4 o;
  o.x = f2bf((v.x - mean)*rstd*g.x + b.x);
  o.y = f2bf((v.y - mean)*rstd*g.y + b.y);
  o.z = f2bf((v.z - mean)*rstd*g.z + b.z);
  o.w = f2bf((v.w - mean)*rstd*g.w + b.w);
  *(ushort4*)(xn + (size_t)token*DM + lane*4) = o;
}

// ---------------- fused head: xp/z/dt sub-GEMMs + chunked scan -> yz -------
// Block = 128 tokens x 64 channels; grid 1536 (1D). q&7 = XCD owns m-tiles
// [xcd*32, xcd*32+32), sweeping 6 ch-panels. 3 sub-GEMMs (R12 inner loop,
// K=256, 8 kt): sub 0 silu->sOut[0](xp), 1 silu->sOut[1](z), 2 softplus->
// sOut[2](dt). sOut layout [128][64] with col^(fq<<4): 2-way banks both ways.
// Then 256 scan units (wave = chunk), all inputs LDS, write yz only.
__global__ __launch_bounds__(256, 2) void s6_head(
    const unsigned short* __restrict__ xn,   // [M,256] bf16
    const unsigned short* __restrict__ Wb,   // [1152,256] bf16 (xp|z|W_eff)
    const float* __restrict__ biasc,         // [1152]
    const float* __restrict__ A_log, const float* __restrict__ D_vec,
    unsigned short* __restrict__ yz)         // [M,384] bf16
{
  constexpr int K = 256, CPR = K/8;
  __shared__ unsigned short sB[64*K];        // 32KB
  __shared__ unsigned short sOut[3][128*64]; // 48KB
  const int t    = threadIdx.x;
  const int lane = t & 63;
  const int w    = t >> 6;
  const int fr   = lane & 15;
  const int fq   = lane >> 4;
  const int wm   = w * 32;

  const int q      = blockIdx.x;
  const int u      = q >> 3;
  const int mtile  = (q & 7) * 32 + (u & 31);   // 0..255
  const int panel  = u >> 5;                    // 0..5
  const int mbase  = mtile * 128;
  const int chbase = panel * 64;

  const unsigned short* gA0 = xn + (size_t)(mbase + wm + fr)*K + fq*8;
  const unsigned short* gA1 = gA0 + (size_t)16*K;
  const unsigned short* sBrE = sB + (size_t)fr*K + ( fq      ^ (fr & 7))*8;
  const unsigned short* sBrO = sB + (size_t)fr*K + ((fq | 4) ^ (fr & 7))*8;

  #pragma unroll
  for (int sub = 0; sub < 3; ++sub) {
    const int nb = sub*DI + chbase;            // weight row base in Wb
    // ---- stage B panel (64 rows x 256 k), 16B-chunk XOR swizzle ----
    #pragma unroll
    for (int i = 0; i < (64*CPR)/256; ++i) {
      int c   = i*256 + t;
      int row = c / CPR;
      int j   = c - row*CPR;
      int jp  = (j & ~7) | ((j & 7) ^ (row & 7));
      __builtin_amdgcn_global_load_lds(AS1(Wb + (size_t)(nb + row)*K + jp*8),
                                       AS3(sB + c*8), 16, 0, 0);
    }
    __syncthreads();   // sB resident (barrier drains vmcnt)

    f32x4 acc[2][4];
    #pragma unroll
    for (int mi = 0; mi < 2; ++mi)
      #pragma unroll
      for (int ni = 0; ni < 4; ++ni) acc[mi][ni] = (f32x4){0.f, 0.f, 0.f, 0.f};

    #pragma unroll
    for (int kt = 0; kt < 8; ++kt) {
      s16x8 a0 = *(const s16x8*)(gA0 + kt*32);
      s16x8 a1 = *(const s16x8*)(gA1 + kt*32);
      const unsigned short* bb = (kt & 1) ? sBrO : sBrE;
      s16x8 bfr[4];
      #pragma unroll
      for (int ni = 0; ni < 4; ++ni)
        bfr[ni] = *(const s16x8*)(bb + ni*16*K + (kt >> 1)*64);
      #pragma unroll
      for (int ni = 0; ni < 4; ++ni) {
        acc[0][ni] = __builtin_amdgcn_mfma_f32_16x16x32_bf16(a0, bfr[ni], acc[0][ni], 0, 0, 0);
        acc[1][ni] = __builtin_amdgcn_mfma_f32_16x16x32_bf16(a1, bfr[ni], acc[1][ni], 0, 0, 0);
      }
    }

    // ---- epilogue: activation -> sOut[sub]; col' = col ^ (fq<<4) ----
    // ((row>>2)&3 == fq for row = wm+mi*16+fq*4+r) -> 64 distinct cols per
    // store instr -> 2 lanes/bank, free.
    #pragma unroll
    for (int ni = 0; ni < 4; ++ni) {
      float bv = biasc[nb + ni*16 + fr];
      int cn = (ni*16 + fr) ^ (fq << 4);
      #pragma unroll
      for (int mi = 0; mi < 2; ++mi) {
        int rm0 = wm + mi*16 + fq*4;
        #pragma unroll
        for (int r = 0; r < 4; ++r) {
          float c = acc[mi][ni][r] + bv;
          c = (sub < 2) ? silu_f(c)
                        : ((c > 20.f) ? c : __logf(1.f + __expf(c)));
          sOut[sub][(rm0 + r)*64 + cn] = f2bf(c);
        }
      }
    }
    __syncthreads();   // sB free for next stage; sOut[sub] visible
  }

  // ---- scan: 256 units = (chunk c = wave, channel d = lane-ish) ----
  {
    const int c  = t >> 6;        // chunk 0..3
    const int d  = t & 63;        // panel-local channel
    const int ch = chbase + d;    // global channel
    float a[DS], h[DS];
    #pragma unroll
    for (int s = 0; s < DS; ++s) { a[s] = -__expf(A_log[ch*DS + s]); h[s] = 0.f; }
    float Dv = D_vec[ch];
    unsigned short* yzp = yz + (size_t)(mbase + c*32)*DI + ch;
    for (int tt = 0; tt < 32; ++tt) {
      int idx = (c*32 + tt)*64 + (d ^ (((tt >> 2) & 3) << 4));
      float xv  = bf2f(sOut[0][idx]);
      float zv  = bf2f(sOut[1][idx]);
      float dtv = bf2f(sOut[2][idx]);
      float y = 0.f;
      #pragma unroll
      for (int s = 0; s < DS; ++s) {
        h[s] = h[s] * __expf(dtv * a[s]) + xv;
        y += h[s];
      }
      yzp[(size_t)tt*DI] = f2bf(y * zv + xv * Dv);
    }
  }
}

// ---------------- persistent-B MFMA GEMM (R12 geometry), EPI=3 only --------
// C[M,N] = A[M,K] @ Bw[N,K]^T + bias + resid -> fp32. Grid (128, GY).
template<int KSTEPS, int MT>
__global__ __launch_bounds__(256, 3) void gemm_out(
    const unsigned short* __restrict__ A,   // [M,K] bf16
    const unsigned short* __restrict__ Bw,  // [N,K] bf16
    const float* __restrict__ bias,         // [N]
    const float* __restrict__ resid, float* __restrict__ o_f)
{
  constexpr int K    = KSTEPS * 32;
  constexpr int CPR  = K / 8;
  __shared__ unsigned short sB[64*K];

  const int t    = threadIdx.x;
  const int lane = t & 63;
  const int w    = t >> 6;
  const int fr   = lane & 15;
  const int fq   = lane >> 4;
  const int wm   = w * 32;

  const int q    = blockIdx.y * 128 + blockIdx.x;
  const int bx2  = (q & 7) * 16 + ((q >> 3) & 15);
  const int by2  = q >> 7;
  const int mbase0 = bx2 * (128 * MT);
  const int nbase  = by2 * 64;

  #pragma unroll
  for (int i = 0; i < (64*CPR)/256; ++i) {
    int c   = i*256 + t;
    int row = c / CPR;
    int j   = c - row*CPR;
    int jp  = (j & ~7) | ((j & 7) ^ (row & 7));
    __builtin_amdgcn_global_load_lds(AS1(Bw + (size_t)(nbase + row)*K + jp*8),
                                     AS3(sB + c*8), 16, 0, 0);
  }

  const unsigned short* sBrE = sB + (size_t)fr*K + ( fq      ^ (fr & 7))*8;
  const unsigned short* sBrO = sB + (size_t)fr*K + ((fq | 4) ^ (fr & 7))*8;

  float bvv[4];
  #pragma unroll
  for (int ni = 0; ni < 4; ++ni) bvv[ni] = bias[nbase + ni*16 + fr];

  __syncthreads();   // B panel resident — the ONLY barrier

  #pragma unroll
  for (int mt = 0; mt < MT; ++mt) {
    const int mbase = mbase0 + mt*128;
    const unsigned short* gA0 = A + (size_t)(mbase + wm + fr)*K + fq*8;
    const unsigned short* gA1 = gA0 + (size_t)16*K;

    f32x4 acc[2][4];
    #pragma unroll
    for (int mi = 0; mi < 2; ++mi)
      #pragma unroll
      for (int ni = 0; ni < 4; ++ni) acc[mi][ni] = (f32x4){0.f, 0.f, 0.f, 0.f};

    #pragma unroll
    for (int kt = 0; kt < KSTEPS; ++kt) {
      s16x8 a0 = *(const s16x8*)(gA0 + kt*32);
      s16x8 a1 = *(const s16x8*)(gA1 + kt*32);
      const unsigned short* bb = (kt & 1) ? sBrO : sBrE;
      s16x8 bfr[4];
      #pragma unroll
      for (int ni = 0; ni < 4; ++ni)
        bfr[ni] = *(const s16x8*)(bb + ni*16*K + (kt >> 1)*64);
      #pragma unroll
      for (int ni = 0; ni < 4; ++ni) {
        acc[0][ni] = __builtin_amdgcn_mfma_f32_16x16x32_bf16(a0, bfr[ni], acc[0][ni], 0, 0, 0);
        acc[1][ni] = __builtin_amdgcn_mfma_f32_16x16x32_bf16(a1, bfr[ni], acc[1][ni], 0, 0, 0);
      }
    }

    #pragma unroll
    for (int ni = 0; ni < 4; ++ni) {
      int gn = nbase + ni*16 + fr;
      #pragma unroll
      for (int mi = 0; mi < 2; ++mi) {
        int gm0 = mbase + wm + mi*16 + fq*4;
        #pragma unroll
        for (int r = 0; r < 4; ++r) {
          size_t gm = (size_t)(gm0 + r);
          o_f[gm*DM + gn] = acc[mi][ni][r] + bvv[ni] + resid[gm*DM + gn];
        }
      }
    }
  }
}

extern "C" void kernel_launch(void* const* d_in, const int* in_sizes, int n_in,
                              void* d_out, int out_size, void* d_ws, size_t ws_size,
                              hipStream_t stream) {
  const float* x     = (const float*)d_in[0];
  const float* gamma = (const float*)d_in[1];
  const float* beta  = (const float*)d_in[2];
  const float* W_in  = (const float*)d_in[3];
  const float* b_in  = (const float*)d_in[4];
  const float* W_dt  = (const float*)d_in[5];
  const float* b_dt  = (const float*)d_in[6];
  const float* A_log = (const float*)d_in[7];
  const float* D_vec = (const float*)d_in[8];
  const float* W_out = (const float*)d_in[9];
  const float* b_out = (const float*)d_in[10];
  float* out = (float*)d_out;

  char* ws = (char*)d_ws;
  size_t off = 0;
  auto alloc = [&](size_t bytes) -> char* {
    char* p = ws + off; off += (bytes + 255) & ~(size_t)255; return p;
  };
  unsigned short* xn    = (unsigned short*)alloc((size_t)M_*DM*2);
  unsigned short* yzb   = (unsigned short*)alloc((size_t)M_*DI*2);
  unsigned short* winb  = (unsigned short*)alloc((size_t)3*DI*DM*2);
  unsigned short* woutb = (unsigned short*)alloc((size_t)DM*DI*2);
  float*          biasc = (float*)alloc((size_t)3*DI*4);

  cvt_kernel<<<dim3((3*DI*DM + 255)/256), 256, 0, stream>>>(W_in, W_out, b_in, winb, woutb, biasc);
  prep_kernel<<<dim3(DI + 2), 256, 0, stream>>>(W_in, b_in, W_dt, b_dt, winb, biasc);
  ln_kernel<<<dim3(M_/4), 256, 0, stream>>>(x, gamma, beta, xn);
  // fused head: xp/z/dt sub-GEMMs + scan -> yz  (xp/z/dt never hit HBM)
  s6_head<<<dim3(6 * 256), 256, 0, stream>>>(xn, winb, biasc, A_log, D_vec, yzb);
  // GEMM3: yz[M,384] @ W_out[256,384]^T + b_out + residual -> out (fp32)
  gemm_out<12, 2><<<dim3(128, DM/64), 256, 0, stream>>>(
      yzb, woutb, b_out, x, out);
}

// Round 12
// 209.810 us; speedup vs baseline: 1.0424x; 1.0424x over previous
//
#include <hip/hip_runtime.h>
#include <stdint.h>

// S6Layer on MI355X. B=8, L=4096, DM=256, DI=384, DS=8, CHUNK=32.
// R18 (this round), from R11 counters (s6_head 78.2us, HBM 5.8%, VALU 44.7%;
// fusion removed 96MB but saved 0us -> HBM not critical path):
//  1. gemm_out: the epilogue was SCATTER-bound (per-scalar fp32 resid/out in
//     fragment order = 16x64B segments/instr; ~1.7TB/s effective on 88MB).
//     Now: MT=1, C-tile (acc+bias) staged to fp32 LDS [128][72] OVERLAID on
//     sB (barrier-protected, 36.9KB<=48KB), then float4-coalesced resid+out
//     (4x256B contiguous per instr). Swizzle generalized to GX=256 (bijective:
//     bx2=(q&7)*32+((q>>3)&31)). LDS 48KB -> 3 blocks/CU.
//  2. s6_head: software-pipeline the 3 sub-GEMMs: issue STAGE(sub+1) DMA
//     right after the post-K-loop barrier, run EPILOGUE(sub) (pure VALU+sOut,
//     no sB access) UNDER the DMA, then barrier (drains vmcnt) -> K-loop.
//     Same 6 barriers; staging latency hidden. Two live acc arrays (aP/aC).
// Order of adds in gemm_out preserved ((acc+bias)+resid) -> bit-identical.
// Pipeline: cvt, prep, ln, s6_head, gemm_out.
#define B_  8
#define L_  4096
#define DM  256
#define DI  384
#define DS  8
#define M_  (B_*L_)   // 32768 tokens

typedef float f32x4 __attribute__((ext_vector_type(4)));
typedef short s16x8 __attribute__((ext_vector_type(8)));

#define AS1(p) ((__attribute__((address_space(1))) void*)(p))
#define AS3(p) ((__attribute__((address_space(3))) void*)(p))

__device__ __forceinline__ unsigned short f2bf(float f) {
  union { float f; uint32_t u; } v; v.f = f;
  uint32_t r = v.u + 0x7FFFu + ((v.u >> 16) & 1u);   // RNE
  return (unsigned short)(r >> 16);
}
__device__ __forceinline__ float bf2f(unsigned short h) {
  union { uint32_t u; float f; } v; v.u = ((uint32_t)h) << 16;
  return v.f;
}
__device__ __forceinline__ float silu_f(float x) {
  return x * __builtin_amdgcn_rcpf(1.f + __expf(-x));
}

// ---------------- weight fp32 -> bf16 (+ b_in copy into combined bias) -----
__global__ __launch_bounds__(256) void cvt_kernel(
    const float* __restrict__ w0, const float* __restrict__ w2,
    const float* __restrict__ b_in,
    unsigned short* __restrict__ o0, unsigned short* __restrict__ o2,
    float* __restrict__ biasc) {
  int i = blockIdx.x * 256 + threadIdx.x;
  if (i < 3*DI*DM) o0[i] = f2bf(w0[i]);
  if (i < DM*DI)   o2[i] = f2bf(w2[i]);
  if (i < 2*DI)    biasc[i] = b_in[i];
}

// ---------------- prep: W_eff = W_dt @ W_in_dt, b_eff = W_dt@b_in_dt + b_dt
__global__ __launch_bounds__(256) void prep_kernel(
    const float* __restrict__ W_in, const float* __restrict__ b_in,
    const float* __restrict__ W_dt, const float* __restrict__ b_dt,
    unsigned short* __restrict__ winb, float* __restrict__ biasc) {
  int nb = blockIdx.x;
  if (nb < DI) {
    int c = threadIdx.x;                 // 0..DM-1
    float acc = 0.f;
    for (int k = 0; k < DI; ++k)
      acc += W_dt[(size_t)nb*DI + k] * W_in[(size_t)(2*DI + k)*DM + c];
    winb[(size_t)(2*DI + nb)*DM + c] = f2bf(acc);
  } else {
    int n = (nb - DI)*256 + threadIdx.x;
    if (n < DI) {
      float acc = b_dt[n];
      for (int k = 0; k < DI; ++k)
        acc += W_dt[(size_t)n*DI + k] * b_in[2*DI + k];
      biasc[2*DI + n] = acc;
    }
  }
}

// ---------------- layernorm: one wave per token ----------------
__global__ __launch_bounds__(256) void ln_kernel(
    const float* __restrict__ x, const float* __restrict__ gamma, const float* __restrict__ beta,
    unsigned short* __restrict__ xn) {
  int token = blockIdx.x * 4 + (threadIdx.x >> 6);
  int lane  = threadIdx.x & 63;
  const float4 v = *(const float4*)(x + (size_t)token*DM + lane*4);
  float s  = v.x + v.y + v.z + v.w;
  float ss = v.x*v.x + v.y*v.y + v.z*v.z + v.w*v.w;
  #pragma unroll
  for (int off = 32; off > 0; off >>= 1) {
    s  += __shfl_xor(s,  off, 64);
    ss += __shfl_xor(ss, off, 64);
  }
  float mean = s * (1.f/DM);
  float var  = ss * (1.f/DM) - mean*mean;
  float rstd = rsqrtf(var + 1e-5f);
  const float4 g = *(const float4*)(gamma + lane*4);
  const float4 b = *(const float4*)(beta  + lane*4);
  ushort4 o;
  o.x = f2bf((v.x - mean)*rstd*g.x + b.x);
  o.y = f2bf((v.y - mean)*rstd*g.y + b.y);
  o.z = f2bf((v.z - mean)*rstd*g.z + b.z);
  o.w = f2bf((v.w - mean)*rstd*g.w + b.w);
  *(ushort4*)(xn + (size_t)token*DM + lane*4) = o;
}

// ---------------- fused head: xp/z/dt sub-GEMMs + chunked scan -> yz -------
// Block = 128 tokens x 64 channels; grid 1536. Pipelined:
//   STAGE(0); bar; KLOOP->aP; [bar; STAGE(s+1); EPI(s); bar; KLOOP]*2; EPI(2);
//   bar; SCAN.  DMA of stage(s+1) hides under EPI(s)'s VALU.
__global__ __launch_bounds__(256, 2) void s6_head(
    const unsigned short* __restrict__ xn,   // [M,256] bf16
    const unsigned short* __restrict__ Wb,   // [1152,256] bf16 (xp|z|W_eff)
    const float* __restrict__ biasc,         // [1152]
    const float* __restrict__ A_log, const float* __restrict__ D_vec,
    unsigned short* __restrict__ yz)         // [M,384] bf16
{
  constexpr int K = 256, CPR = K/8;
  __shared__ unsigned short sB[64*K];        // 32KB
  __shared__ unsigned short sOut[3][128*64]; // 48KB
  const int t    = threadIdx.x;
  const int lane = t & 63;
  const int w    = t >> 6;
  const int fr   = lane & 15;
  const int fq   = lane >> 4;
  const int wm   = w * 32;

  const int q      = blockIdx.x;
  const int u      = q >> 3;
  const int mtile  = (q & 7) * 32 + (u & 31);   // 0..255
  const int panel  = u >> 5;                    // 0..5
  const int mbase  = mtile * 128;
  const int chbase = panel * 64;

  const unsigned short* gA0 = xn + (size_t)(mbase + wm + fr)*K + fq*8;
  const unsigned short* gA1 = gA0 + (size_t)16*K;
  const unsigned short* sBrE = sB + (size_t)fr*K + ( fq      ^ (fr & 7))*8;
  const unsigned short* sBrO = sB + (size_t)fr*K + ((fq | 4) ^ (fr & 7))*8;

  auto STAGE = [&](int sub) {
    const int nb = sub*DI + chbase;
    #pragma unroll
    for (int i = 0; i < (64*CPR)/256; ++i) {
      int c   = i*256 + t;
      int row = c / CPR;
      int j   = c - row*CPR;
      int jp  = (j & ~7) | ((j & 7) ^ (row & 7));
      __builtin_amdgcn_global_load_lds(AS1(Wb + (size_t)(nb + row)*K + jp*8),
                                       AS3(sB + c*8), 16, 0, 0);
    }
  };
  auto KLOOP = [&](f32x4 (&acc)[2][4]) {
    #pragma unroll
    for (int mi = 0; mi < 2; ++mi)
      #pragma unroll
      for (int ni = 0; ni < 4; ++ni) acc[mi][ni] = (f32x4){0.f, 0.f, 0.f, 0.f};
    #pragma unroll
    for (int kt = 0; kt < 8; ++kt) {
      s16x8 a0 = *(const s16x8*)(gA0 + kt*32);
      s16x8 a1 = *(const s16x8*)(gA1 + kt*32);
      const unsigned short* bb = (kt & 1) ? sBrO : sBrE;
      s16x8 bfr[4];
      #pragma unroll
      for (int ni = 0; ni < 4; ++ni)
        bfr[ni] = *(const s16x8*)(bb + ni*16*K + (kt >> 1)*64);
      #pragma unroll
      for (int ni = 0; ni < 4; ++ni) {
        acc[0][ni] = __builtin_amdgcn_mfma_f32_16x16x32_bf16(a0, bfr[ni], acc[0][ni], 0, 0, 0);
        acc[1][ni] = __builtin_amdgcn_mfma_f32_16x16x32_bf16(a1, bfr[ni], acc[1][ni], 0, 0, 0);
      }
    }
  };
  auto EPI = [&](f32x4 (&acc)[2][4], int sub) {
    const int nb = sub*DI + chbase;
    const bool sl = (sub < 2);
    #pragma unroll
    for (int ni = 0; ni < 4; ++ni) {
      float bv = biasc[nb + ni*16 + fr];
      int cn = (ni*16 + fr) ^ (fq << 4);
      #pragma unroll
      for (int mi = 0; mi < 2; ++mi) {
        int rm0 = wm + mi*16 + fq*4;
        #pragma unroll
        for (int r = 0; r < 4; ++r) {
          float c = acc[mi][ni][r] + bv;
          c = sl ? silu_f(c) : ((c > 20.f) ? c : __logf(1.f + __expf(c)));
          sOut[sub][(rm0 + r)*64 + cn] = f2bf(c);
        }
      }
    }
  };

  f32x4 aP[2][4], aC[2][4];
  STAGE(0);
  __syncthreads();                 // sB(0) resident
  KLOOP(aP);
  __syncthreads();                 // all waves done reading sB(0)
  STAGE(1);                        // DMA under the epilogue VALU
  EPI(aP, 0);
  __syncthreads();                 // drains vmcnt -> sB(1) resident
  KLOOP(aC);
  __syncthreads();
  STAGE(2);
  EPI(aC, 1);
  __syncthreads();
  KLOOP(aP);
  EPI(aP, 2);
  __syncthreads();                 // sOut[0..2] visible to all waves

  // ---- scan: 256 units = (chunk c = wave, channel d = lane-ish) ----
  {
    const int c  = t >> 6;        // chunk 0..3
    const int d  = t & 63;        // panel-local channel
    const int ch = chbase + d;    // global channel
    float a[DS], h[DS];
    #pragma unroll
    for (int s = 0; s < DS; ++s) { a[s] = -__expf(A_log[ch*DS + s]); h[s] = 0.f; }
    float Dv = D_vec[ch];
    unsigned short* yzp = yz + (size_t)(mbase + c*32)*DI + ch;
    for (int tt = 0; tt < 32; ++tt) {
      int idx = (c*32 + tt)*64 + (d ^ (((tt >> 2) & 3) << 4));
      float xv  = bf2f(sOut[0][idx]);
      float zv  = bf2f(sOut[1][idx]);
      float dtv = bf2f(sOut[2][idx]);
      float y = 0.f;
      #pragma unroll
      for (int s = 0; s < DS; ++s) {
        h[s] = h[s] * __expf(dtv * a[s]) + xv;
        y += h[s];
      }
      yzp[(size_t)tt*DI] = f2bf(y * zv + xv * Dv);
    }
  }
}

// ---------------- GEMM3: yz @ Wout^T + b_out + resid, coalesced epilogue ---
// C[M,256] = A[M,384] @ Bw[256,384]^T. Block 256 thr, tile 128M x 64N, MT=1.
// Grid (256, 4); swizzle: q=by*256+bx, bx2=(q&7)*32+((q>>3)&31) (bijective),
// by2=q>>8. After K-loop: acc+bias staged to fp32 LDS [128][72] OVERLAID on
// sB (barrier-protected), then float4-coalesced resid read + out write
// (4 x 256B contiguous segments per instruction vs 16 x 64B scatter before).
__global__ __launch_bounds__(256, 3) void gemm_out(
    const unsigned short* __restrict__ A,   // [M,384] bf16 (yz)
    const unsigned short* __restrict__ Bw,  // [256,384] bf16
    const float* __restrict__ bias,         // [256]
    const float* __restrict__ resid, float* __restrict__ o_f)
{
  constexpr int K = 384, CPR = K/8;
  __shared__ unsigned short sB[64*K];       // 48KB
  float* sC = (float*)sB;                   // overlay: [128][72] fp32 = 36.9KB

  const int t    = threadIdx.x;
  const int lane = t & 63;
  const int w    = t >> 6;
  const int fr   = lane & 15;
  const int fq   = lane >> 4;
  const int wm   = w * 32;

  const int q    = blockIdx.y * 256 + blockIdx.x;
  const int bx2  = (q & 7) * 32 + ((q >> 3) & 31);
  const int by2  = q >> 8;
  const int mbase = bx2 * 128;
  const int nbase = by2 * 64;

  #pragma unroll
  for (int i = 0; i < (64*CPR)/256; ++i) {
    int c   = i*256 + t;
    int row = c / CPR;
    int j   = c - row*CPR;
    int jp  = (j & ~7) | ((j & 7) ^ (row & 7));
    __builtin_amdgcn_global_load_lds(AS1(Bw + (size_t)(nbase + row)*K + jp*8),
                                     AS3(sB + c*8), 16, 0, 0);
  }

  const unsigned short* sBrE = sB + (size_t)fr*K + ( fq      ^ (fr & 7))*8;
  const unsigned short* sBrO = sB + (size_t)fr*K + ((fq | 4) ^ (fr & 7))*8;

  float bvv[4];
  #pragma unroll
  for (int ni = 0; ni < 4; ++ni) bvv[ni] = bias[nbase + ni*16 + fr];

  __syncthreads();   // B panel resident

  const unsigned short* gA0 = A + (size_t)(mbase + wm + fr)*K + fq*8;
  const unsigned short* gA1 = gA0 + (size_t)16*K;

  f32x4 acc[2][4];
  #pragma unroll
  for (int mi = 0; mi < 2; ++mi)
    #pragma unroll
    for (int ni = 0; ni < 4; ++ni) acc[mi][ni] = (f32x4){0.f, 0.f, 0.f, 0.f};

  #pragma unroll
  for (int kt = 0; kt < 12; ++kt) {
    s16x8 a0 = *(const s16x8*)(gA0 + kt*32);
    s16x8 a1 = *(const s16x8*)(gA1 + kt*32);
    const unsigned short* bb = (kt & 1) ? sBrO : sBrE;
    s16x8 bfr[4];
    #pragma unroll
    for (int ni = 0; ni < 4; ++ni)
      bfr[ni] = *(const s16x8*)(bb + ni*16*K + (kt >> 1)*64);
    #pragma unroll
    for (int ni = 0; ni < 4; ++ni) {
      acc[0][ni] = __builtin_amdgcn_mfma_f32_16x16x32_bf16(a0, bfr[ni], acc[0][ni], 0, 0, 0);
      acc[1][ni] = __builtin_amdgcn_mfma_f32_16x16x32_bf16(a1, bfr[ni], acc[1][ni], 0, 0, 0);
    }
  }

  __syncthreads();   // every wave done reading sB -> safe to overlay sC

  // stage acc+bias (C layout: col=fr, row=fq*4+r per 16x16 tile, m89)
  #pragma unroll
  for (int ni = 0; ni < 4; ++ni)
    #pragma unroll
    for (int mi = 0; mi < 2; ++mi)
      #pragma unroll
      for (int r = 0; r < 4; ++r)
        sC[(wm + mi*16 + fq*4 + r)*72 + ni*16 + fr] = acc[mi][ni][r] + bvv[ni];

  __syncthreads();   // sC visible to all waves

  // coalesced: thread t covers cols (t&15)*4..+3 of rows (t>>4)+16*it
  const int rr = t >> 4, cl = (t & 15) * 4;
  #pragma unroll
  for (int it = 0; it < 8; ++it) {
    int row = rr + it*16;
    const float4 c  = *(const float4*)&sC[row*72 + cl];
    const float4 rv = *(const float4*)(resid + (size_t)(mbase + row)*DM + nbase + cl);
    float4 o;
    o.x = c.x + rv.x; o.y = c.y + rv.y; o.z = c.z + rv.z; o.w = c.w + rv.w;
    *(float4*)(o_f + (size_t)(mbase + row)*DM + nbase + cl) = o;
  }
}

extern "C" void kernel_launch(void* const* d_in, const int* in_sizes, int n_in,
                              void* d_out, int out_size, void* d_ws, size_t ws_size,
                              hipStream_t stream) {
  const float* x     = (const float*)d_in[0];
  const float* gamma = (const float*)d_in[1];
  const float* beta  = (const float*)d_in[2];
  const float* W_in  = (const float*)d_in[3];
  const float* b_in  = (const float*)d_in[4];
  const float* W_dt  = (const float*)d_in[5];
  const float* b_dt  = (const float*)d_in[6];
  const float* A_log = (const float*)d_in[7];
  const float* D_vec = (const float*)d_in[8];
  const float* W_out = (const float*)d_in[9];
  const float* b_out = (const float*)d_in[10];
  float* out = (float*)d_out;

  char* ws = (char*)d_ws;
  size_t off = 0;
  auto alloc = [&](size_t bytes) -> char* {
    char* p = ws + off; off += (bytes + 255) & ~(size_t)255; return p;
  };
  unsigned short* xn    = (unsigned short*)alloc((size_t)M_*DM*2);
  unsigned short* yzb   = (unsigned short*)alloc((size_t)M_*DI*2);
  unsigned short* winb  = (unsigned short*)alloc((size_t)3*DI*DM*2);
  unsigned short* woutb = (unsigned short*)alloc((size_t)DM*DI*2);
  float*          biasc = (float*)alloc((size_t)3*DI*4);

  cvt_kernel<<<dim3((3*DI*DM + 255)/256), 256, 0, stream>>>(W_in, W_out, b_in, winb, woutb, biasc);
  prep_kernel<<<dim3(DI + 2), 256, 0, stream>>>(W_in, b_in, W_dt, b_dt, winb, biasc);
  ln_kernel<<<dim3(M_/4), 256, 0, stream>>>(x, gamma, beta, xn);
  // fused head: xp/z/dt sub-GEMMs + scan -> yz  (xp/z/dt never hit HBM)
  s6_head<<<dim3(6 * 256), 256, 0, stream>>>(xn, winb, biasc, A_log, D_vec, yzb);
  // GEMM3: yz[M,384] @ W_out[256,384]^T + b_out + residual -> out (fp32)
  gemm_out<<<dim3(256, DM/64), 256, 0, stream>>>(yzb, woutb, b_out, x, out);
}

// Round 14
// 198.452 us; speedup vs baseline: 1.1021x; 1.0572x over previous
//
#include <hip/hip_runtime.h>
#include <stdint.h>

// S6Layer on MI355X. B=8, L=4096, DM=256, DI=384, DS=8, CHUNK=32.
// R20 = R19 with the compile fix (__exp2f -> exp2f; HIP device exp2f maps to
// v_exp_f32 which IS 2^x natively). R19 content, untested until now:
//  1. s6_head: A-frags (xn tile) are IDENTICAL across the 3 sub-GEMMs ->
//     preload all 16 s16x8 frags to registers ONCE (issued before the B-DMA
//     barrier, latency absorbed there). KLOOP(1)/(2) become pure LDS+MFMA.
//     Scan: pre-scale a2[s]=a[s]*log2e -> exp2f(dtv*a2[s]) (-8 vmul/iter).
//  2. prep split: prep1 grid(384,4) k-chunks of 96, 4 independent partial
//     chains -> fp32 scratch; prep2 sums 4 partials + b_eff, converts bf16.
//     Parallelism 386->1540 blocks, chain 384->24. Deterministic, no atomics.
// R18 kept: gemm_out MT=1 grid(256,4) with LDS-staged coalesced fp32 epilogue;
// s6_head 3-sub pipeline (STAGE under EPI); R16 W_eff algebra; R12 swizzles.
// Pipeline: cvt, prep1, prep2, ln, s6_head, gemm_out.
#define B_  8
#define L_  4096
#define DM  256
#define DI  384
#define DS  8
#define M_  (B_*L_)   // 32768 tokens

typedef float f32x4 __attribute__((ext_vector_type(4)));
typedef short s16x8 __attribute__((ext_vector_type(8)));

#define AS1(p) ((__attribute__((address_space(1))) void*)(p))
#define AS3(p) ((__attribute__((address_space(3))) void*)(p))

__device__ __forceinline__ unsigned short f2bf(float f) {
  union { float f; uint32_t u; } v; v.f = f;
  uint32_t r = v.u + 0x7FFFu + ((v.u >> 16) & 1u);   // RNE
  return (unsigned short)(r >> 16);
}
__device__ __forceinline__ float bf2f(unsigned short h) {
  union { uint32_t u; float f; } v; v.u = ((uint32_t)h) << 16;
  return v.f;
}
__device__ __forceinline__ float silu_f(float x) {
  return x * __builtin_amdgcn_rcpf(1.f + __expf(-x));
}

// ---------------- weight fp32 -> bf16 (+ b_in copy into combined bias) -----
__global__ __launch_bounds__(256) void cvt_kernel(
    const float* __restrict__ w0, const float* __restrict__ w2,
    const float* __restrict__ b_in,
    unsigned short* __restrict__ o0, unsigned short* __restrict__ o2,
    float* __restrict__ biasc) {
  int i = blockIdx.x * 256 + threadIdx.x;
  if (i < 3*DI*DM) o0[i] = f2bf(w0[i]);
  if (i < DM*DI)   o2[i] = f2bf(w2[i]);
  if (i < 2*DI)    biasc[i] = b_in[i];
}

// ---------------- prep1: W_eff partials over k-chunks of 96 ----------------
// grid (384, 4), 256 thr. scr[(n*4+kc)*256+c] = sum_{k in chunk} Wdt[n,k]*
// W_in[2DI+k, c]. Wave 0 also reduces the b_in partial -> bscr[n*4+kc].
__global__ __launch_bounds__(256) void prep1_kernel(
    const float* __restrict__ W_in, const float* __restrict__ b_in,
    const float* __restrict__ W_dt,
    float* __restrict__ scr, float* __restrict__ bscr) {
  const int n  = blockIdx.x;
  const int kc = blockIdx.y;
  const int c  = threadIdx.x;
  const int kb = kc * 96;
  const float* wd = W_dt + (size_t)n*DI + kb;
  const float* wi = W_in + (size_t)(2*DI + kb)*DM + c;
  float p0 = 0.f, p1 = 0.f, p2 = 0.f, p3 = 0.f;
  #pragma unroll
  for (int k = 0; k < 96; k += 4) {
    p0 += wd[k+0] * wi[(size_t)(k+0)*DM];
    p1 += wd[k+1] * wi[(size_t)(k+1)*DM];
    p2 += wd[k+2] * wi[(size_t)(k+2)*DM];
    p3 += wd[k+3] * wi[(size_t)(k+3)*DM];
  }
  scr[(size_t)(n*4 + kc)*256 + c] = (p0 + p1) + (p2 + p3);
  if (c < 64) {
    float p = wd[c] * b_in[2*DI + kb + c];
    if (c < 32) p += wd[64 + c] * b_in[2*DI + kb + 64 + c];
    #pragma unroll
    for (int off = 32; off > 0; off >>= 1) p += __shfl_down(p, off, 64);
    if (c == 0) bscr[n*4 + kc] = p;
  }
}

// ---------------- prep2: sum 4 partials -> winb dt-slice; b_eff -> biasc ---
__global__ __launch_bounds__(256) void prep2_kernel(
    const float* __restrict__ scr, const float* __restrict__ bscr,
    const float* __restrict__ b_dt,
    unsigned short* __restrict__ winb, float* __restrict__ biasc) {
  const int n = blockIdx.x, c = threadIdx.x;
  const float* s = scr + (size_t)n*4*256 + c;
  winb[(size_t)(2*DI + n)*DM + c] = f2bf((s[0] + s[256]) + (s[512] + s[768]));
  if (c == 0)
    biasc[2*DI + n] = b_dt[n] + ((bscr[n*4] + bscr[n*4+1]) + (bscr[n*4+2] + bscr[n*4+3]));
}

// ---------------- layernorm: one wave per token ----------------
__global__ __launch_bounds__(256) void ln_kernel(
    const float* __restrict__ x, const float* __restrict__ gamma, const float* __restrict__ beta,
    unsigned short* __restrict__ xn) {
  int token = blockIdx.x * 4 + (threadIdx.x >> 6);
  int lane  = threadIdx.x & 63;
  const float4 v = *(const float4*)(x + (size_t)token*DM + lane*4);
  float s  = v.x + v.y + v.z + v.w;
  float ss = v.x*v.x + v.y*v.y + v.z*v.z + v.w*v.w;
  #pragma unroll
  for (int off = 32; off > 0; off >>= 1) {
    s  += __shfl_xor(s,  off, 64);
    ss += __shfl_xor(ss, off, 64);
  }
  float mean = s * (1.f/DM);
  float var  = ss * (1.f/DM) - mean*mean;
  float rstd = rsqrtf(var + 1e-5f);
  const float4 g = *(const float4*)(gamma + lane*4);
  const float4 b = *(const float4*)(beta  + lane*4);
  ushort4 o;
  o.x = f2bf((v.x - mean)*rstd*g.x + b.x);
  o.y = f2bf((v.y - mean)*rstd*g.y + b.y);
  o.z = f2bf((v.z - mean)*rstd*g.z + b.z);
  o.w = f2bf((v.w - mean)*rstd*g.w + b.w);
  *(ushort4*)(xn + (size_t)token*DM + lane*4) = o;
}

// ---------------- fused head: xp/z/dt sub-GEMMs + chunked scan -> yz -------
// Block = 128 tokens x 64 channels; grid 1536. A-frags preloaded ONCE to 16
// s16x8 regs (A identical across subs); pipelined STAGE-under-EPI as R18.
__global__ __launch_bounds__(256, 2) void s6_head(
    const unsigned short* __restrict__ xn,   // [M,256] bf16
    const unsigned short* __restrict__ Wb,   // [1152,256] bf16 (xp|z|W_eff)
    const float* __restrict__ biasc,         // [1152]
    const float* __restrict__ A_log, const float* __restrict__ D_vec,
    unsigned short* __restrict__ yz)         // [M,384] bf16
{
  constexpr int K = 256, CPR = K/8;
  __shared__ unsigned short sB[64*K];        // 32KB
  __shared__ unsigned short sOut[3][128*64]; // 48KB
  const int t    = threadIdx.x;
  const int lane = t & 63;
  const int w    = t >> 6;
  const int fr   = lane & 15;
  const int fq   = lane >> 4;
  const int wm   = w * 32;

  const int q      = blockIdx.x;
  const int u      = q >> 3;
  const int mtile  = (q & 7) * 32 + (u & 31);   // 0..255
  const int panel  = u >> 5;                    // 0..5
  const int mbase  = mtile * 128;
  const int chbase = panel * 64;

  const unsigned short* gA0 = xn + (size_t)(mbase + wm + fr)*K + fq*8;
  const unsigned short* gA1 = gA0 + (size_t)16*K;
  const unsigned short* sBrE = sB + (size_t)fr*K + ( fq      ^ (fr & 7))*8;
  const unsigned short* sBrO = sB + (size_t)fr*K + ((fq | 4) ^ (fr & 7))*8;

  // ---- preload ALL A-frags once (shared by the 3 sub-GEMMs) ----
  s16x8 afr[8][2];
  #pragma unroll
  for (int kt = 0; kt < 8; ++kt) {
    afr[kt][0] = *(const s16x8*)(gA0 + kt*32);
    afr[kt][1] = *(const s16x8*)(gA1 + kt*32);
  }

  auto STAGE = [&](int sub) {
    const int nb = sub*DI + chbase;
    #pragma unroll
    for (int i = 0; i < (64*CPR)/256; ++i) {
      int c   = i*256 + t;
      int row = c / CPR;
      int j   = c - row*CPR;
      int jp  = (j & ~7) | ((j & 7) ^ (row & 7));
      __builtin_amdgcn_global_load_lds(AS1(Wb + (size_t)(nb + row)*K + jp*8),
                                       AS3(sB + c*8), 16, 0, 0);
    }
  };
  auto KLOOP = [&](f32x4 (&acc)[2][4]) {
    #pragma unroll
    for (int mi = 0; mi < 2; ++mi)
      #pragma unroll
      for (int ni = 0; ni < 4; ++ni) acc[mi][ni] = (f32x4){0.f, 0.f, 0.f, 0.f};
    #pragma unroll
    for (int kt = 0; kt < 8; ++kt) {
      const unsigned short* bb = (kt & 1) ? sBrO : sBrE;
      s16x8 bfr[4];
      #pragma unroll
      for (int ni = 0; ni < 4; ++ni)
        bfr[ni] = *(const s16x8*)(bb + ni*16*K + (kt >> 1)*64);
      #pragma unroll
      for (int ni = 0; ni < 4; ++ni) {
        acc[0][ni] = __builtin_amdgcn_mfma_f32_16x16x32_bf16(afr[kt][0], bfr[ni], acc[0][ni], 0, 0, 0);
        acc[1][ni] = __builtin_amdgcn_mfma_f32_16x16x32_bf16(afr[kt][1], bfr[ni], acc[1][ni], 0, 0, 0);
      }
    }
  };
  auto EPI = [&](f32x4 (&acc)[2][4], int sub) {
    const int nb = sub*DI + chbase;
    const bool sl = (sub < 2);
    #pragma unroll
    for (int ni = 0; ni < 4; ++ni) {
      float bv = biasc[nb + ni*16 + fr];
      int cn = (ni*16 + fr) ^ (fq << 4);
      #pragma unroll
      for (int mi = 0; mi < 2; ++mi) {
        int rm0 = wm + mi*16 + fq*4;
        #pragma unroll
        for (int r = 0; r < 4; ++r) {
          float c = acc[mi][ni][r] + bv;
          c = sl ? silu_f(c) : ((c > 20.f) ? c : __logf(1.f + __expf(c)));
          sOut[sub][(rm0 + r)*64 + cn] = f2bf(c);
        }
      }
    }
  };

  f32x4 aP[2][4], aC[2][4];
  STAGE(0);
  __syncthreads();                 // sB(0) + afr resident
  KLOOP(aP);
  __syncthreads();                 // all waves done reading sB(0)
  STAGE(1);                        // DMA under the epilogue VALU
  EPI(aP, 0);
  __syncthreads();                 // drains vmcnt -> sB(1) resident
  KLOOP(aC);
  __syncthreads();
  STAGE(2);
  EPI(aC, 1);
  __syncthreads();
  KLOOP(aP);
  EPI(aP, 2);
  __syncthreads();                 // sOut[0..2] visible to all waves

  // ---- scan: 256 units = (chunk c = wave, channel d = lane) ----
  {
    const int c  = t >> 6;        // chunk 0..3
    const int d  = t & 63;        // panel-local channel
    const int ch = chbase + d;    // global channel
    float a2[DS], h[DS];
    #pragma unroll
    for (int s = 0; s < DS; ++s) {
      a2[s] = -__expf(A_log[ch*DS + s]) * 1.44269504f;   // pre-scale: exp->exp2
      h[s] = 0.f;
    }
    float Dv = D_vec[ch];
    unsigned short* yzp = yz + (size_t)(mbase + c*32)*DI + ch;
    for (int tt = 0; tt < 32; ++tt) {
      int idx = (c*32 + tt)*64 + (d ^ (((tt >> 2) & 3) << 4));
      float xv  = bf2f(sOut[0][idx]);
      float zv  = bf2f(sOut[1][idx]);
      float dtv = bf2f(sOut[2][idx]);
      float y = 0.f;
      #pragma unroll
      for (int s = 0; s < DS; ++s) {
        h[s] = h[s] * exp2f(dtv * a2[s]) + xv;
        y += h[s];
      }
      yzp[(size_t)tt*DI] = f2bf(y * zv + xv * Dv);
    }
  }
}

// ---------------- GEMM3: yz @ Wout^T + b_out + resid, coalesced epilogue ---
__global__ __launch_bounds__(256, 3) void gemm_out(
    const unsigned short* __restrict__ A,   // [M,384] bf16 (yz)
    const unsigned short* __restrict__ Bw,  // [256,384] bf16
    const float* __restrict__ bias,         // [256]
    const float* __restrict__ resid, float* __restrict__ o_f)
{
  constexpr int K = 384, CPR = K/8;
  __shared__ unsigned short sB[64*K];       // 48KB
  float* sC = (float*)sB;                   // overlay: [128][72] fp32 = 36.9KB

  const int t    = threadIdx.x;
  const int lane = t & 63;
  const int w    = t >> 6;
  const int fr   = lane & 15;
  const int fq   = lane >> 4;
  const int wm   = w * 32;

  const int q    = blockIdx.y * 256 + blockIdx.x;
  const int bx2  = (q & 7) * 32 + ((q >> 3) & 31);
  const int by2  = q >> 8;
  const int mbase = bx2 * 128;
  const int nbase = by2 * 64;

  #pragma unroll
  for (int i = 0; i < (64*CPR)/256; ++i) {
    int c   = i*256 + t;
    int row = c / CPR;
    int j   = c - row*CPR;
    int jp  = (j & ~7) | ((j & 7) ^ (row & 7));
    __builtin_amdgcn_global_load_lds(AS1(Bw + (size_t)(nbase + row)*K + jp*8),
                                     AS3(sB + c*8), 16, 0, 0);
  }

  const unsigned short* sBrE = sB + (size_t)fr*K + ( fq      ^ (fr & 7))*8;
  const unsigned short* sBrO = sB + (size_t)fr*K + ((fq | 4) ^ (fr & 7))*8;

  float bvv[4];
  #pragma unroll
  for (int ni = 0; ni < 4; ++ni) bvv[ni] = bias[nbase + ni*16 + fr];

  __syncthreads();   // B panel resident

  const unsigned short* gA0 = A + (size_t)(mbase + wm + fr)*K + fq*8;
  const unsigned short* gA1 = gA0 + (size_t)16*K;

  f32x4 acc[2][4];
  #pragma unroll
  for (int mi = 0; mi < 2; ++mi)
    #pragma unroll
    for (int ni = 0; ni < 4; ++ni) acc[mi][ni] = (f32x4){0.f, 0.f, 0.f, 0.f};

  #pragma unroll
  for (int kt = 0; kt < 12; ++kt) {
    s16x8 a0 = *(const s16x8*)(gA0 + kt*32);
    s16x8 a1 = *(const s16x8*)(gA1 + kt*32);
    const unsigned short* bb = (kt & 1) ? sBrO : sBrE;
    s16x8 bfr[4];
    #pragma unroll
    for (int ni = 0; ni < 4; ++ni)
      bfr[ni] = *(const s16x8*)(bb + ni*16*K + (kt >> 1)*64);
    #pragma unroll
    for (int ni = 0; ni < 4; ++ni) {
      acc[0][ni] = __builtin_amdgcn_mfma_f32_16x16x32_bf16(a0, bfr[ni], acc[0][ni], 0, 0, 0);
      acc[1][ni] = __builtin_amdgcn_mfma_f32_16x16x32_bf16(a1, bfr[ni], acc[1][ni], 0, 0, 0);
    }
  }

  __syncthreads();   // every wave done reading sB -> safe to overlay sC

  #pragma unroll
  for (int ni = 0; ni < 4; ++ni)
    #pragma unroll
    for (int mi = 0; mi < 2; ++mi)
      #pragma unroll
      for (int r = 0; r < 4; ++r)
        sC[(wm + mi*16 + fq*4 + r)*72 + ni*16 + fr] = acc[mi][ni][r] + bvv[ni];

  __syncthreads();   // sC visible to all waves

  const int rr = t >> 4, cl = (t & 15) * 4;
  #pragma unroll
  for (int it = 0; it < 8; ++it) {
    int row = rr + it*16;
    const float4 c  = *(const float4*)&sC[row*72 + cl];
    const float4 rv = *(const float4*)(resid + (size_t)(mbase + row)*DM + nbase + cl);
    float4 o;
    o.x = c.x + rv.x; o.y = c.y + rv.y; o.z = c.z + rv.z; o.w = c.w + rv.w;
    *(float4*)(o_f + (size_t)(mbase + row)*DM + nbase + cl) = o;
  }
}

extern "C" void kernel_launch(void* const* d_in, const int* in_sizes, int n_in,
                              void* d_out, int out_size, void* d_ws, size_t ws_size,
                              hipStream_t stream) {
  const float* x     = (const float*)d_in[0];
  const float* gamma = (const float*)d_in[1];
  const float* beta  = (const float*)d_in[2];
  const float* W_in  = (const float*)d_in[3];
  const float* b_in  = (const float*)d_in[4];
  const float* W_dt  = (const float*)d_in[5];
  const float* b_dt  = (const float*)d_in[6];
  const float* A_log = (const float*)d_in[7];
  const float* D_vec = (const float*)d_in[8];
  const float* W_out = (const float*)d_in[9];
  const float* b_out = (const float*)d_in[10];
  float* out = (float*)d_out;

  char* ws = (char*)d_ws;
  size_t off = 0;
  auto alloc = [&](size_t bytes) -> char* {
    char* p = ws + off; off += (bytes + 255) & ~(size_t)255; return p;
  };
  unsigned short* xn    = (unsigned short*)alloc((size_t)M_*DM*2);
  unsigned short* yzb   = (unsigned short*)alloc((size_t)M_*DI*2);
  unsigned short* winb  = (unsigned short*)alloc((size_t)3*DI*DM*2);
  unsigned short* woutb = (unsigned short*)alloc((size_t)DM*DI*2);
  float*          biasc = (float*)alloc((size_t)3*DI*4);
  float*          scr   = (float*)alloc((size_t)DI*4*256*4);
  float*          bscr  = (float*)alloc((size_t)DI*4*4);

  cvt_kernel<<<dim3((3*DI*DM + 255)/256), 256, 0, stream>>>(W_in, W_out, b_in, winb, woutb, biasc);
  prep1_kernel<<<dim3(DI, 4), 256, 0, stream>>>(W_in, b_in, W_dt, scr, bscr);
  prep2_kernel<<<dim3(DI), 256, 0, stream>>>(scr, bscr, b_dt, winb, biasc);
  ln_kernel<<<dim3(M_/4), 256, 0, stream>>>(x, gamma, beta, xn);
  // fused head: xp/z/dt sub-GEMMs + scan -> yz  (xp/z/dt never hit HBM)
  s6_head<<<dim3(6 * 256), 256, 0, stream>>>(xn, winb, biasc, A_log, D_vec, yzb);
  // GEMM3: yz[M,384] @ W_out[256,384]^T + b_out + residual -> out (fp32)
  gemm_out<<<dim3(256, DM/64), 256, 0, stream>>>(yzb, woutb, b_out, x, out);
}